// Round 1
// baseline (145.749 us; speedup 1.0000x reference)
//
#include <hip/hip_runtime.h>
#include <hip/hip_bf16.h>

#define N_NODES 8192
#define FIN 512
#define FOUT 64
#define LRELU_ALPHA 0.2f

typedef __attribute__((ext_vector_type(8))) short short8;
typedef __attribute__((ext_vector_type(4))) float floatx4;

__device__ __forceinline__ short f2bf_bits(float x) {
    __hip_bfloat16 h = __float2bfloat16(x);
    union { __hip_bfloat16 b; short s; } u; u.b = h; return u.s;
}

// p = adj>0 ? exp(leakyrelu(ssrc + sdst)) : 0   (ssrc has a_b folded in)
__device__ __forceinline__ float pval(float ssrc, float sd, int adjv) {
    float e = ssrc + sd;
    e = fmaxf(e, LRELU_ALPHA * e);        // leaky relu (works for both signs)
    float pv = __expf(e);
    return adjv > 0 ? pv : 0.0f;
}

// Kernel A: h = x@W + b; s_src = h@a[:64] + a_b; s_dst = h@a[64:]; hbfT = bf16(h)^T [64][N]
// One wave computes 4 rows; lane f owns feature f.
__global__ __launch_bounds__(256) void gat_h(
    const float* __restrict__ x, const float* __restrict__ W,
    const float* __restrict__ bias, const float* __restrict__ a,
    const float* __restrict__ a_b,
    float* __restrict__ s_src, float* __restrict__ s_dst,
    unsigned short* __restrict__ hbfT)
{
    const int lane = threadIdx.x & 63;
    const int wave = threadIdx.x >> 6;
    const int r0 = (blockIdx.x * 4 + wave) * 4;   // 4 rows per wave

    float acc0 = 0.f, acc1 = 0.f, acc2 = 0.f, acc3 = 0.f;
    const float* x0 = x + (size_t)r0 * FIN;

    #pragma unroll 4
    for (int k = 0; k < FIN; k += 4) {
        float4 xa = *reinterpret_cast<const float4*>(x0 + k);
        float4 xb = *reinterpret_cast<const float4*>(x0 + FIN + k);
        float4 xc = *reinterpret_cast<const float4*>(x0 + 2 * FIN + k);
        float4 xd = *reinterpret_cast<const float4*>(x0 + 3 * FIN + k);
        float w0 = W[(k + 0) * FOUT + lane];
        float w1 = W[(k + 1) * FOUT + lane];
        float w2 = W[(k + 2) * FOUT + lane];
        float w3 = W[(k + 3) * FOUT + lane];
        acc0 = fmaf(xa.w, w3, fmaf(xa.z, w2, fmaf(xa.y, w1, fmaf(xa.x, w0, acc0))));
        acc1 = fmaf(xb.w, w3, fmaf(xb.z, w2, fmaf(xb.y, w1, fmaf(xb.x, w0, acc1))));
        acc2 = fmaf(xc.w, w3, fmaf(xc.z, w2, fmaf(xc.y, w1, fmaf(xc.x, w0, acc2))));
        acc3 = fmaf(xd.w, w3, fmaf(xd.z, w2, fmaf(xd.y, w1, fmaf(xd.x, w0, acc3))));
    }
    float bb = bias[lane];
    acc0 += bb; acc1 += bb; acc2 += bb; acc3 += bb;

    // store bf16 h transposed: hbfT[f][r0..r0+3] as one 8B store
    ushort4 pk;
    pk.x = (unsigned short)f2bf_bits(acc0);
    pk.y = (unsigned short)f2bf_bits(acc1);
    pk.z = (unsigned short)f2bf_bits(acc2);
    pk.w = (unsigned short)f2bf_bits(acc3);
    *reinterpret_cast<ushort4*>(hbfT + (size_t)lane * N_NODES + r0) = pk;

    // s_src/s_dst: wave reductions over the 64 features
    float asrc = a[lane], adst = a[FOUT + lane];
    float ab = a_b[0];
    float ss0 = acc0 * asrc, ss1 = acc1 * asrc, ss2 = acc2 * asrc, ss3 = acc3 * asrc;
    float sd0 = acc0 * adst, sd1 = acc1 * adst, sd2 = acc2 * adst, sd3 = acc3 * adst;
    #pragma unroll
    for (int m = 32; m >= 1; m >>= 1) {
        ss0 += __shfl_xor(ss0, m); ss1 += __shfl_xor(ss1, m);
        ss2 += __shfl_xor(ss2, m); ss3 += __shfl_xor(ss3, m);
        sd0 += __shfl_xor(sd0, m); sd1 += __shfl_xor(sd1, m);
        sd2 += __shfl_xor(sd2, m); sd3 += __shfl_xor(sd3, m);
    }
    if (lane == 0) {
        float4 vs = { ss0 + ab, ss1 + ab, ss2 + ab, ss3 + ab };  // fold a_b into s_src
        float4 vd = { sd0, sd1, sd2, sd3 };
        *reinterpret_cast<float4*>(s_src + r0) = vs;
        *reinterpret_cast<float4*>(s_dst + r0) = vd;
    }
}

// Kernel B: per block: 16 rows; 4 waves split J; P built in-register as MFMA A-frags;
// B-frags loaded from global H^T (L2-resident). Epilogue: cross-wave reduce, /denom, ELU.
__global__ __launch_bounds__(256) void gat_attn(
    const int* __restrict__ adj,
    const float* __restrict__ s_src,
    const float* __restrict__ s_dst,
    const unsigned short* __restrict__ hbfT,
    float* __restrict__ out)
{
    const int lane = threadIdx.x & 63;
    const int wave = threadIdx.x >> 6;
    const int i0 = blockIdx.x * 16;
    const int rowA = i0 + (lane & 15);
    const int ko = (lane >> 4) * 8;   // k-offset within a 32-wide K step

    const float ssrc = s_src[rowA];   // a_b already folded in
    floatx4 acc[4] = { {0.f,0.f,0.f,0.f},{0.f,0.f,0.f,0.f},
                       {0.f,0.f,0.f,0.f},{0.f,0.f,0.f,0.f} };
    float denom = 0.f;

    const size_t adjRow = (size_t)rowA * N_NODES;

    for (int jt = wave; jt < N_NODES / 64; jt += 4) {
        const int j0 = jt * 64;
        #pragma unroll
        for (int kk = 0; kk < 2; ++kk) {
            const int jb = j0 + kk * 32 + ko;
            int4 A0 = *reinterpret_cast<const int4*>(adj + adjRow + jb);
            int4 A1 = *reinterpret_cast<const int4*>(adj + adjRow + jb + 4);
            float4 S0 = *reinterpret_cast<const float4*>(s_dst + jb);
            float4 S1 = *reinterpret_cast<const float4*>(s_dst + jb + 4);
            float p0 = pval(ssrc, S0.x, A0.x);
            float p1 = pval(ssrc, S0.y, A0.y);
            float p2 = pval(ssrc, S0.z, A0.z);
            float p3 = pval(ssrc, S0.w, A0.w);
            float p4 = pval(ssrc, S1.x, A1.x);
            float p5 = pval(ssrc, S1.y, A1.y);
            float p6 = pval(ssrc, S1.z, A1.z);
            float p7 = pval(ssrc, S1.w, A1.w);
            denom += ((p0 + p1) + (p2 + p3)) + ((p4 + p5) + (p6 + p7));
            short8 af;
            af[0] = f2bf_bits(p0); af[1] = f2bf_bits(p1);
            af[2] = f2bf_bits(p2); af[3] = f2bf_bits(p3);
            af[4] = f2bf_bits(p4); af[5] = f2bf_bits(p5);
            af[6] = f2bf_bits(p6); af[7] = f2bf_bits(p7);
            #pragma unroll
            for (int n = 0; n < 4; ++n) {
                short8 bf = *reinterpret_cast<const short8*>(
                    hbfT + (size_t)(n * 16 + (lane & 15)) * N_NODES + jb);
                acc[n] = __builtin_amdgcn_mfma_f32_16x16x32_bf16(af, bf, acc[n], 0, 0, 0);
            }
        }
    }

    // denom: reduce the 4 lane-groups (lanes with same lane&15 share a row)
    denom += __shfl_xor(denom, 16);
    denom += __shfl_xor(denom, 32);

    __shared__ floatx4 redbuf[4][4][64];   // [wave][n][lane] = 16 KB
    __shared__ float dred[4][16];          // per-wave denom partials
    #pragma unroll
    for (int n = 0; n < 4; ++n) redbuf[wave][n][lane] = acc[n];
    if (lane < 16) dred[wave][lane] = denom;
    __syncthreads();

    // wave w finishes N-tile n = w
    floatx4 facc = redbuf[0][wave][lane];
    facc += redbuf[1][wave][lane];
    facc += redbuf[2][wave][lane];
    facc += redbuf[3][wave][lane];

    #pragma unroll
    for (int e = 0; e < 4; ++e) {
        const int r2 = (lane >> 4) * 4 + e;   // C row within the 16-row tile
        float dn = dred[0][r2] + dred[1][r2] + dred[2][r2] + dred[3][r2];
        float val = facc[e] / dn;
        val = val > 0.f ? val : (__expf(val) - 1.f);   // ELU (alpha=1)
        out[(size_t)(i0 + r2) * FOUT + wave * 16 + (lane & 15)] = val;
    }
}

extern "C" void kernel_launch(void* const* d_in, const int* in_sizes, int n_in,
                              void* d_out, int out_size, void* d_ws, size_t ws_size,
                              hipStream_t stream) {
    const float* x   = (const float*)d_in[0];
    const int*   adj = (const int*)d_in[1];
    const float* W   = (const float*)d_in[2];
    const float* b   = (const float*)d_in[3];
    const float* a   = (const float*)d_in[4];
    const float* a_b = (const float*)d_in[5];
    float* out = (float*)d_out;

    char* ws = (char*)d_ws;
    float* s_src = (float*)ws;                         // 32 KB
    float* s_dst = (float*)(ws + 32 * 1024);           // 32 KB
    unsigned short* hbfT = (unsigned short*)(ws + 64 * 1024); // 1 MB

    hipLaunchKernelGGL(gat_h, dim3(N_NODES / 16), dim3(256), 0, stream,
                       x, W, b, a, a_b, s_src, s_dst, hbfT);
    hipLaunchKernelGGL(gat_attn, dim3(N_NODES / 16), dim3(256), 0, stream,
                       adj, s_src, s_dst, hbfT, out);
}

// Round 3
// 132.087 us; speedup vs baseline: 1.1034x; 1.1034x over previous
//
#include <hip/hip_runtime.h>
#include <hip/hip_bf16.h>

#define N_NODES 8192
#define FIN 512
#define FOUT 64
#define LRELU_ALPHA 0.2f

typedef __attribute__((ext_vector_type(8))) short short8;
typedef __attribute__((ext_vector_type(4))) float floatx4;

static __device__ __forceinline__ short f2bf_bits(float x) {
    union { __hip_bfloat16 b; short s; } u; u.b = __float2bfloat16(x); return u.s;
}

// p = adj>0 ? exp(leakyrelu(ssrc + sdst)) : 0   (a_b folded into ssrc)
static __device__ __forceinline__ float pval(float ssrc, float sd, int adjv) {
    float e = ssrc + sd;
    e = fmaxf(e, LRELU_ALPHA * e);
    float pv = __expf(e);
    return adjv > 0 ? pv : 0.0f;
}

// Kernel A: h = x@W + b; s_src = h@a[:64] + a_b; s_dst = h@a[64:];
// hswz = bf16(h)^T in MFMA-B-fragment-major layout:
//   hswz[((ks*4 + n)*64 + lane)*8 + e] = h[j = ks*32 + (lane>>4)*8 + e][f = n*16 + (lane&15)]
// so gat_attn's B-frag load is a single coalesced short8 at lane*16B.
__global__ __launch_bounds__(256) void gat_h(
    const float* __restrict__ x, const float* __restrict__ W,
    const float* __restrict__ bias, const float* __restrict__ a,
    const float* __restrict__ a_b,
    float* __restrict__ s_src, float* __restrict__ s_dst,
    unsigned short* __restrict__ hswz)
{
    const int lane = threadIdx.x & 63;
    const int wave = threadIdx.x >> 6;
    const int r0 = (blockIdx.x * 4 + wave) * 4;   // 4 rows per wave

    float acc0 = 0.f, acc1 = 0.f, acc2 = 0.f, acc3 = 0.f;
    const float* x0 = x + (size_t)r0 * FIN;

    #pragma unroll 4
    for (int k = 0; k < FIN; k += 4) {
        float4 xa = *reinterpret_cast<const float4*>(x0 + k);
        float4 xb = *reinterpret_cast<const float4*>(x0 + FIN + k);
        float4 xc = *reinterpret_cast<const float4*>(x0 + 2 * FIN + k);
        float4 xd = *reinterpret_cast<const float4*>(x0 + 3 * FIN + k);
        float w0 = W[(k + 0) * FOUT + lane];
        float w1 = W[(k + 1) * FOUT + lane];
        float w2 = W[(k + 2) * FOUT + lane];
        float w3 = W[(k + 3) * FOUT + lane];
        acc0 = fmaf(xa.w, w3, fmaf(xa.z, w2, fmaf(xa.y, w1, fmaf(xa.x, w0, acc0))));
        acc1 = fmaf(xb.w, w3, fmaf(xb.z, w2, fmaf(xb.y, w1, fmaf(xb.x, w0, acc1))));
        acc2 = fmaf(xc.w, w3, fmaf(xc.z, w2, fmaf(xc.y, w1, fmaf(xc.x, w0, acc2))));
        acc3 = fmaf(xd.w, w3, fmaf(xd.z, w2, fmaf(xd.y, w1, fmaf(xd.x, w0, acc3))));
    }
    float bb = bias[lane];
    acc0 += bb; acc1 += bb; acc2 += bb; acc3 += bb;

    // fragment-major bf16 store: rows r0..r0+3 (same ks, same lane_dst, e = (r0&7)+0..3)
    {
        const int ks = r0 >> 5;
        const int n = lane >> 4;
        const int lane_dst = (lane & 15) + (((r0 >> 3) & 3) << 4);
        const int e0 = r0 & 7;
        ushort4 pk;
        pk.x = (unsigned short)f2bf_bits(acc0);
        pk.y = (unsigned short)f2bf_bits(acc1);
        pk.z = (unsigned short)f2bf_bits(acc2);
        pk.w = (unsigned short)f2bf_bits(acc3);
        *reinterpret_cast<ushort4*>(
            hswz + (size_t)((ks * 4 + n) * 64 + lane_dst) * 8 + e0) = pk;
    }

    float asrc = a[lane], adst = a[FOUT + lane];
    float ab = a_b[0];
    float ss0 = acc0 * asrc, ss1 = acc1 * asrc, ss2 = acc2 * asrc, ss3 = acc3 * asrc;
    float sd0 = acc0 * adst, sd1 = acc1 * adst, sd2 = acc2 * adst, sd3 = acc3 * adst;
    #pragma unroll
    for (int m = 32; m >= 1; m >>= 1) {
        ss0 += __shfl_xor(ss0, m); ss1 += __shfl_xor(ss1, m);
        ss2 += __shfl_xor(ss2, m); ss3 += __shfl_xor(ss3, m);
        sd0 += __shfl_xor(sd0, m); sd1 += __shfl_xor(sd1, m);
        sd2 += __shfl_xor(sd2, m); sd3 += __shfl_xor(sd3, m);
    }
    if (lane == 0) {
        float4 vs = { ss0 + ab, ss1 + ab, ss2 + ab, ss3 + ab };
        float4 vd = { sd0, sd1, sd2, sd3 };
        *reinterpret_cast<float4*>(s_src + r0) = vs;
        *reinterpret_cast<float4*>(s_dst + r0) = vd;
    }
}

// Coalesced adj tile stage: 16 rows x 64 cols into per-wave LDS buffer via
// global_load_lds. LDS dest is linear (lane*16B); the XOR swizzle
// (c ^= (r&7)<<2, 16B granules) is applied to the *global source* column so the
// fragment ds_read_b128 below is bank-conflict-free (rule: both-sides-or-neither).
static __device__ __forceinline__ void stage_tile(const int* __restrict__ adj,
                                                  int i0, int j0, int lane,
                                                  char* ldsbase) {
    #pragma unroll
    for (int t = 0; t < 4; ++t) {
        const int r = t * 4 + (lane >> 4);
        const int u = (lane & 15) * 4;
        const int col = u ^ ((r & 7) << 2);
        const int* g = adj + (size_t)(i0 + r) * N_NODES + j0 + col;
        __builtin_amdgcn_global_load_lds(
            (const __attribute__((address_space(1))) int*)g,
            (__attribute__((address_space(3))) int*)(ldsbase + t * 1024),
            16, 0, 0);
    }
}

// Kernel B: block = 16 rows x 8 waves; wave w owns jt = w, w+8, ... (J split 8-way,
// no barriers in main loop — per-wave-private double-buffered adj LDS tiles).
// Sync scheme: conservative vmcnt(0) at top of each iteration (drains the
// prefetch issued one full compute-phase earlier); prefetch for t+1 is issued
// AFTER the drain so it overlaps all of compute(t). No counted vmcnt.
__global__ __launch_bounds__(512, 4) void gat_attn(
    const int* __restrict__ adj,
    const float* __restrict__ s_src,
    const float* __restrict__ s_dst,
    const unsigned short* __restrict__ hswz,
    float* __restrict__ out)
{
    __shared__ __align__(16) char smem[65536];   // 8 waves x 2 bufs x 4KB; epilogue overlays

    const int lane = threadIdx.x & 63;
    const int wave = threadIdx.x >> 6;
    const int i0 = blockIdx.x * 16;
    const int rowA = i0 + (lane & 15);
    const int ko = (lane >> 4) * 8;

    const float ssrc = s_src[rowA];
    floatx4 acc[4] = { {0.f,0.f,0.f,0.f},{0.f,0.f,0.f,0.f},
                       {0.f,0.f,0.f,0.f},{0.f,0.f,0.f,0.f} };
    float denom = 0.f;

    char* buf0 = smem + wave * 8192;
    char* buf1 = buf0 + 4096;

    const int NT = (N_NODES / 64) / 8;   // 16 tiles per wave
    int jt = wave;
    stage_tile(adj, i0, jt * 64, lane, buf0);

    for (int t = 0; t < NT; ++t) {
        const int* cur = (const int*)((t & 1) ? buf1 : buf0);
        char* nxt = (t & 1) ? buf0 : buf1;

        // drain: guarantees stage(t)'s DMA (issued last iteration) has landed.
        asm volatile("s_waitcnt vmcnt(0)" ::: "memory");
        __builtin_amdgcn_sched_barrier(0);

        if (t + 1 < NT) stage_tile(adj, i0, (jt + 8) * 64, lane, nxt);

        const int j0 = jt * 64;
        const int r = lane & 15;
        const int swz = (r & 7) << 2;
        #pragma unroll
        for (int kk = 0; kk < 2; ++kk) {
            const int c0 = kk * 32 + ko;
            int4 A0 = *reinterpret_cast<const int4*>(cur + r * 64 + (c0 ^ swz));
            int4 A1 = *reinterpret_cast<const int4*>(cur + r * 64 + ((c0 + 4) ^ swz));
            const int jb = j0 + c0;
            float4 S0 = *reinterpret_cast<const float4*>(s_dst + jb);
            float4 S1 = *reinterpret_cast<const float4*>(s_dst + jb + 4);
            float p0 = pval(ssrc, S0.x, A0.x);
            float p1 = pval(ssrc, S0.y, A0.y);
            float p2 = pval(ssrc, S0.z, A0.z);
            float p3 = pval(ssrc, S0.w, A0.w);
            float p4 = pval(ssrc, S1.x, A1.x);
            float p5 = pval(ssrc, S1.y, A1.y);
            float p6 = pval(ssrc, S1.z, A1.z);
            float p7 = pval(ssrc, S1.w, A1.w);
            denom += ((p0 + p1) + (p2 + p3)) + ((p4 + p5) + (p6 + p7));
            short8 af;
            af[0] = f2bf_bits(p0); af[1] = f2bf_bits(p1);
            af[2] = f2bf_bits(p2); af[3] = f2bf_bits(p3);
            af[4] = f2bf_bits(p4); af[5] = f2bf_bits(p5);
            af[6] = f2bf_bits(p6); af[7] = f2bf_bits(p7);
            const int ks = jt * 2 + kk;
            #pragma unroll
            for (int n = 0; n < 4; ++n) {
                short8 bf = *reinterpret_cast<const short8*>(
                    hswz + (size_t)((ks * 4 + n) * 64 + lane) * 8);
                acc[n] = __builtin_amdgcn_mfma_f32_16x16x32_bf16(af, bf, acc[n], 0, 0, 0);
            }
        }
        jt += 8;
    }

    // reduce denom over the 4 ko-groups (lanes sharing lane&15)
    denom += __shfl_xor(denom, 16);
    denom += __shfl_xor(denom, 32);

    __syncthreads();   // all waves done reading adj LDS; reuse it for reduction
    floatx4* redbuf = (floatx4*)smem;          // [8][4][64] = 32 KB
    float* dred = (float*)(smem + 32768);      // [8][16]
    #pragma unroll
    for (int n = 0; n < 4; ++n) redbuf[(wave * 4 + n) * 64 + lane] = acc[n];
    if (lane < 16) dred[wave * 16 + lane] = denom;
    __syncthreads();

    if (wave < 4) {
        floatx4 facc = redbuf[wave * 64 + lane];
        #pragma unroll
        for (int v = 1; v < 8; ++v) facc += redbuf[(v * 4 + wave) * 64 + lane];
        #pragma unroll
        for (int e = 0; e < 4; ++e) {
            const int r2 = (lane >> 4) * 4 + e;
            float dn = 0.f;
            #pragma unroll
            for (int v = 0; v < 8; ++v) dn += dred[v * 16 + r2];
            float val = facc[e] / dn;
            val = val > 0.f ? val : (__expf(val) - 1.f);   // ELU
            out[(size_t)(i0 + r2) * FOUT + wave * 16 + (lane & 15)] = val;
        }
    }
}

extern "C" void kernel_launch(void* const* d_in, const int* in_sizes, int n_in,
                              void* d_out, int out_size, void* d_ws, size_t ws_size,
                              hipStream_t stream) {
    const float* x   = (const float*)d_in[0];
    const int*   adj = (const int*)d_in[1];
    const float* W   = (const float*)d_in[2];
    const float* b   = (const float*)d_in[3];
    const float* a   = (const float*)d_in[4];
    const float* a_b = (const float*)d_in[5];
    float* out = (float*)d_out;

    char* ws = (char*)d_ws;
    float* s_src = (float*)ws;                                 // 32 KB
    float* s_dst = (float*)(ws + 32 * 1024);                   // 32 KB
    unsigned short* hswz = (unsigned short*)(ws + 64 * 1024);  // 1 MB

    hipLaunchKernelGGL(gat_h, dim3(N_NODES / 16), dim3(256), 0, stream,
                       x, W, b, a, a_b, s_src, s_dst, hswz);
    hipLaunchKernelGGL(gat_attn, dim3(N_NODES / 16), dim3(512), 0, stream,
                       adj, s_src, s_dst, hswz, out);
}